// Round 6
// baseline (282.247 us; speedup 1.0000x reference)
//
#include <hip/hip_runtime.h>

#define Bc 8
#define Tc 4096
#define Dc 768
#define Hc 12
#define HDc 64
#define Kc 32
#define TD3 2304
#define WQKV_F (TD3 * Dc)          // 1,769,472 floats
#define WALL_F ((TD3 + Dc) * Dc)   // 2,359,296 floats (wqkv + wout)
#define XS_F (Bc * Kc * Dc)        //   196,608 floats

typedef __attribute__((ext_vector_type(8))) short short8;
typedef __attribute__((ext_vector_type(4))) short short4v;
typedef __attribute__((ext_vector_type(4))) float float4v;

__device__ __forceinline__ float bf2f(unsigned short u) {
    unsigned v = ((unsigned)u) << 16;
    return __builtin_bit_cast(float, v);
}
__device__ __forceinline__ unsigned short f2bf(float f) {
    unsigned u = __builtin_bit_cast(unsigned, f);
    u += 0x7FFFu + ((u >> 16) & 1u);   // RNE
    return (unsigned short)(u >> 16);
}
__device__ __forceinline__ void split8(const float* p, short8& hi, short8& lo) {
#pragma unroll
    for (int i = 0; i < 8; ++i) {
        unsigned short h = f2bf(p[i]);
        hi[i] = (short)h;
        lo[i] = (short)f2bf(p[i] - bf2f(h));
    }
}
__device__ __forceinline__ void split4(const float4v v, short4v& h, short4v& l) {
#pragma unroll
    for (int q = 0; q < 4; ++q) {
        unsigned short hb = f2bf(v[q]);
        h[q] = (short)hb;
        l[q] = (short)f2bf(v[q] - bf2f(hb));
    }
}

// ---------------------------------------------------------------------------
// L1 (fused): bids [0,512) = k1 spectral GEMM (R1-exact body); bids
// [512,2816) = weight fp32 -> bf16 hi/lo plane conversion co-tenants.
// (validated R5, unchanged)
// ---------------------------------------------------------------------------
__global__ __launch_bounds__(256) void k1_fused(const float* __restrict__ x,
                                                const float* __restrict__ sb,
                                                const float* __restrict__ wqkv,
                                                const float* __restrict__ wout,
                                                float* __restrict__ pb,
                                                short* __restrict__ w_hi,
                                                short* __restrict__ w_lo) {
    __shared__ float xt[32 * 193];
    __shared__ float st[32 * 33];

    int tid = threadIdx.x;
    int bid = blockIdx.x;

    if (bid >= 512) {                  // ---- weight conversion half
        int i = ((bid - 512) * 256 + tid) * 4;
        const float* src = (i < WQKV_F) ? (wqkv + i) : (wout + (i - WQKV_F));
        float4v v = *(const float4v*)src;
        short4v h, l;
        split4(v, h, l);
        *(short4v*)(w_hi + i) = h;
        *(short4v*)(w_lo + i) = l;
        return;
    }

    // ---- k1 half (R1-exact)
    int w    = tid >> 6;
    int lane = tid & 63;
    int col  = lane & 15;
    int quad = lane >> 4;

    int b  = bid >> 6;
    int dt = (bid >> 4) & 3;
    int tc = bid & 15;
    int d0 = dt * 192;
    size_t bT = (size_t)b * Tc + (size_t)tc * 256;

    float4v acc[2][3];
#pragma unroll
    for (int mi = 0; mi < 2; ++mi)
#pragma unroll
        for (int ni = 0; ni < 3; ++ni) acc[mi][ni] = (float4v){0.f, 0.f, 0.f, 0.f};

    for (int ks = 0; ks < 8; ++ks) {
        __syncthreads();
#pragma unroll
        for (int i = 0; i < 6; ++i) {
            int f4  = tid + i * 256;
            int row = f4 / 48, c4 = f4 % 48;
            float4v v = *(const float4v*)&x[(bT + ks * 32 + row) * Dc + d0 + c4 * 4];
#pragma unroll
            for (int q = 0; q < 4; ++q) xt[row * 193 + c4 * 4 + q] = v[q];
        }
        {
            int row = tid >> 3, c4 = tid & 7;
            float4v v = *(const float4v*)&sb[(bT + ks * 32 + row) * Kc + c4 * 4];
#pragma unroll
            for (int q = 0; q < 4; ++q) st[row * 33 + c4 * 4 + q] = v[q];
        }
        __syncthreads();

        short8 ah[2], al[2];
#pragma unroll
        for (int mi = 0; mi < 2; ++mi) {
            float av[8];
#pragma unroll
            for (int j = 0; j < 8; ++j)
                av[j] = st[(quad * 8 + j) * 33 + mi * 16 + col];
            split8(av, ah[mi], al[mi]);
        }
#pragma unroll
        for (int ni = 0; ni < 3; ++ni) {
            int nc = (w * 3 + ni) * 16 + col;
            float bv[8];
#pragma unroll
            for (int j = 0; j < 8; ++j)
                bv[j] = xt[(quad * 8 + j) * 193 + nc];
            short8 bh, bl;
            split8(bv, bh, bl);
#pragma unroll
            for (int mi = 0; mi < 2; ++mi) {
                acc[mi][ni] = __builtin_amdgcn_mfma_f32_16x16x32_bf16(ah[mi], bh, acc[mi][ni], 0, 0, 0);
                acc[mi][ni] = __builtin_amdgcn_mfma_f32_16x16x32_bf16(al[mi], bh, acc[mi][ni], 0, 0, 0);
                acc[mi][ni] = __builtin_amdgcn_mfma_f32_16x16x32_bf16(ah[mi], bl, acc[mi][ni], 0, 0, 0);
            }
        }
    }

    float* pbp = pb + (size_t)tc * XS_F;
#pragma unroll
    for (int mi = 0; mi < 2; ++mi)
#pragma unroll
        for (int ni = 0; ni < 3; ++ni)
#pragma unroll
            for (int r = 0; r < 4; ++r) {
                int kk = mi * 16 + quad * 4 + r;
                int dd = d0 + (w * 3 + ni) * 16 + col;
                pbp[((size_t)(b * Kc + kk)) * Dc + dd] = acc[mi][ni][r];
            }
}

// reduce 16 partials -> xs bf16 hi/lo planes (validated, unchanged)
__global__ __launch_bounds__(256) void k1r_reduce(const float* __restrict__ pb,
                                                  short* __restrict__ xs_hi,
                                                  short* __restrict__ xs_lo) {
    int i = (blockIdx.x * 256 + threadIdx.x) * 4;
    float4v s = (float4v){0.f, 0.f, 0.f, 0.f};
#pragma unroll
    for (int p = 0; p < 16; ++p) {
        float4v v = *(const float4v*)(pb + (size_t)p * XS_F + i);
#pragma unroll
        for (int q = 0; q < 4; ++q) s[q] += v[q];
    }
    short4v h, l;
    split4(s, h, l);
    *(short4v*)(xs_hi + i) = h;
    *(short4v*)(xs_lo + i) = l;
}

// K2: pure-plane GEMM (validated, unchanged: grid 288, wave tile 32x16)
__global__ __launch_bounds__(256) void k2_qkv(const short* __restrict__ xs_hi,
                                              const short* __restrict__ xs_lo,
                                              const short* __restrict__ w_hi,
                                              const short* __restrict__ w_lo,
                                              float* __restrict__ c1) {
    int lane = threadIdx.x & 63;
    int w    = threadIdx.x >> 6;
    int m    = lane & 15, quad = lane >> 4;
    int mb = blockIdx.x & 7;
    int nb = blockIdx.x >> 3;
    int m0 = mb * 32;
    int n0 = nb * 64 + w * 16;

    const short* a0h = xs_hi + (size_t)(m0 + m) * Dc + quad * 8;
    const short* a0l = xs_lo + (size_t)(m0 + m) * Dc + quad * 8;
    const short* a1h = a0h + (size_t)16 * Dc;
    const short* a1l = a0l + (size_t)16 * Dc;
    const short* bhp = w_hi + (size_t)(n0 + m) * Dc + quad * 8;
    const short* blp = w_lo + (size_t)(n0 + m) * Dc + quad * 8;

    float4v acc0 = (float4v){0.f, 0.f, 0.f, 0.f};
    float4v acc1 = (float4v){0.f, 0.f, 0.f, 0.f};
#pragma unroll 4
    for (int s = 0; s < 24; ++s) {
        short8 bh = *(const short8*)(bhp + s * 32);
        short8 bl = *(const short8*)(blp + s * 32);
        short8 h0 = *(const short8*)(a0h + s * 32);
        short8 l0 = *(const short8*)(a0l + s * 32);
        short8 h1 = *(const short8*)(a1h + s * 32);
        short8 l1 = *(const short8*)(a1l + s * 32);
        acc0 = __builtin_amdgcn_mfma_f32_16x16x32_bf16(h0, bh, acc0, 0, 0, 0);
        acc0 = __builtin_amdgcn_mfma_f32_16x16x32_bf16(l0, bh, acc0, 0, 0, 0);
        acc0 = __builtin_amdgcn_mfma_f32_16x16x32_bf16(h0, bl, acc0, 0, 0, 0);
        acc1 = __builtin_amdgcn_mfma_f32_16x16x32_bf16(h1, bh, acc1, 0, 0, 0);
        acc1 = __builtin_amdgcn_mfma_f32_16x16x32_bf16(l1, bh, acc1, 0, 0, 0);
        acc1 = __builtin_amdgcn_mfma_f32_16x16x32_bf16(h1, bl, acc1, 0, 0, 0);
    }
    float* cp0 = c1 + (size_t)(m0 + quad * 4) * TD3 + n0 + m;
    float* cp1 = cp0 + (size_t)16 * TD3;
#pragma unroll
    for (int r = 0; r < 4; ++r) {
        cp0[(size_t)r * TD3] = acc0[r];
        cp1[(size_t)r * TD3] = acc1[r];
    }
}

// ---------------------------------------------------------------------------
// K4 (+FHN): per block, stage fhn for its 64 rows x 12 heads into LDS
// (replaces the separate 12-block k3 launch), then the validated plane GEMM
// proj[r,e] = sum_c (fhn*v_spec)[r,c] * wout[e,c], epilogue -> pT planes.
// Grid 192; block covers rows r0..r0+63 (r0 = 64*(bid&3)).
// ---------------------------------------------------------------------------
__global__ __launch_bounds__(256) void k4_proj(const float* __restrict__ c1,
                                               const float* __restrict__ sfilt,
                                               const short* __restrict__ wo_hi,
                                               const short* __restrict__ wo_lo,
                                               short* __restrict__ pT_hi,
                                               short* __restrict__ pT_lo) {
    __shared__ float fh[64][13];       // +1 pad
    int tid = threadIdx.x;
    int r0  = 64 * (blockIdx.x & 3);

    // FHN stage: 768 (row,h) pairs, 3 per thread
    for (int u = tid; u < 768; u += 256) {
        int h = u >> 6, row_l = u & 63;
        int r = r0 + row_l;
        int kk = r & 31;
        const float* qp = c1 + (size_t)r * TD3 + h * HDc;
        const float* kp = qp + Dc;
        float s = 0.f;
#pragma unroll
        for (int dd = 0; dd < HDc; dd += 4) {
            float4v qv = *(const float4v*)(qp + dd);
            float4v kv = *(const float4v*)(kp + dd);
#pragma unroll
            for (int q2 = 0; q2 < 4; ++q2) s = fmaf(qv[q2], kv[q2], s);
        }
        s *= 0.125f;
        float filt = 1.f / (1.f + __expf(-sfilt[h * 32 + kk]));
        s *= filt;
        float as    = fabsf(s);
        float scale = fmaxf(as, 1e-6f);
        float sn    = s / scale;
        float gate  = 1.f / (1.f + __expf(-(as - 0.5f) * 10.f));
        float I     = sn * (0.1f + 0.9f * gate);
        const float alpha = 0.08f;
        const float denom = 1.064f;
        float v = 0.f, w = 0.f;
#pragma unroll
        for (int it = 0; it < 2; ++it) {
            float dv = v - (v * v * v) / 3.f - w + I;
            float vn = v + dv;
            float wn = (w + (vn + 0.7f) * alpha) / denom;
            v = fminf(fmaxf(vn, -3.f), 3.f);
            w = fminf(fmaxf(wn, -3.f), 3.f);
        }
        fh[row_l][h] = v * scale;
    }
    __syncthreads();

    int wave = blockIdx.x * 4 + (tid >> 6);
    int lane = tid & 63;
    int mb = wave & 15;
    int nt = wave >> 4;
    int m0 = mb * 16, n0 = nt * 16;
    int m = lane & 15, quad = lane >> 4;
    int row_l = (tid >> 6) * 16 + m;   // = m0 + m - r0

    const short* bhp = wo_hi + (size_t)(n0 + m) * Dc + quad * 8;
    const short* blp = wo_lo + (size_t)(n0 + m) * Dc + quad * 8;

    int r = m0 + m;
    const float* apx = c1 + (size_t)r * TD3 + 2 * Dc + quad * 8;

    float4v acc = (float4v){0.f, 0.f, 0.f, 0.f};
#pragma unroll 4
    for (int s = 0; s < 24; ++s) {
        int h = (s * 32 + quad * 8) >> 6;
        float f = fh[row_l][h];
        float av[8];
#pragma unroll
        for (int i = 0; i < 8; ++i) av[i] = apx[s * 32 + i] * f;
        short8 ah, al;
        split8(av, ah, al);
        short8 bh = *(const short8*)(bhp + s * 32);
        short8 bl = *(const short8*)(blp + s * 32);
        acc = __builtin_amdgcn_mfma_f32_16x16x32_bf16(ah, bh, acc, 0, 0, 0);
        acc = __builtin_amdgcn_mfma_f32_16x16x32_bf16(al, bh, acc, 0, 0, 0);
        acc = __builtin_amdgcn_mfma_f32_16x16x32_bf16(ah, bl, acc, 0, 0, 0);
    }
    short4v hv, lv;
    split4(acc, hv, lv);
    size_t o = (size_t)(n0 + m) * (Bc * Kc) + m0 + quad * 4;   // pT[e][r]
    *(short4v*)(pT_hi + o) = hv;
    *(short4v*)(pT_lo + o) = lv;
}

// ---------------------------------------------------------------------------
// K5: out[b,t,e] = sum_k sb[b,t,k] * proj[b,k,e] — LDS-free, barrier-free.
// A = raw fp32 sb + one split8 (R5 form); B = pT bf16 planes, 16B L2 loads
// (R2-validated addressing). Grid 2048 = 8b x 64tt x 4et.
// ---------------------------------------------------------------------------
__global__ __launch_bounds__(256) void k5_out(const short* __restrict__ pT_hi,
                                              const short* __restrict__ pT_lo,
                                              const float* __restrict__ sb,
                                              float* __restrict__ out) {
    int tid  = threadIdx.x;
    int w    = tid >> 6;
    int lane = tid & 63;
    int col  = lane & 15;
    int quad = lane >> 4;

    int bid = blockIdx.x;
    int b  = bid >> 8;
    int tt = (bid >> 2) & 63;
    int et = bid & 3;
    int t0 = tt * 64 + w * 16;
    int e0 = et * 192;

    const float* apx = sb + ((size_t)b * Tc + t0 + col) * Kc + quad * 8;
    short8 ah, al;
    split8(apx, ah, al);

    float4v acc[12];
#pragma unroll
    for (int ni = 0; ni < 12; ++ni) acc[ni] = (float4v){0.f, 0.f, 0.f, 0.f};

#pragma unroll
    for (int ni = 0; ni < 12; ++ni) {
        size_t bo = (size_t)(e0 + ni * 16 + col) * (Bc * Kc) + b * 32 + quad * 8;
        short8 bh = *(const short8*)(pT_hi + bo);
        short8 bl = *(const short8*)(pT_lo + bo);
        acc[ni] = __builtin_amdgcn_mfma_f32_16x16x32_bf16(ah, bh, acc[ni], 0, 0, 0);
        acc[ni] = __builtin_amdgcn_mfma_f32_16x16x32_bf16(al, bh, acc[ni], 0, 0, 0);
        acc[ni] = __builtin_amdgcn_mfma_f32_16x16x32_bf16(ah, bl, acc[ni], 0, 0, 0);
    }

    float* op = out + ((size_t)b * Tc + t0 + quad * 4) * Dc + e0 + col;
#pragma unroll
    for (int ni = 0; ni < 12; ++ni)
#pragma unroll
        for (int r = 0; r < 4; ++r)
            op[(size_t)r * Dc + ni * 16] = acc[ni][r];
}

extern "C" void kernel_launch(void* const* d_in, const int* in_sizes, int n_in,
                              void* d_out, int out_size, void* d_ws, size_t ws_size,
                              hipStream_t stream) {
    const float* x     = (const float*)d_in[0];
    const float* sb    = (const float*)d_in[1];
    const float* wqkv  = (const float*)d_in[2];
    const float* wout  = (const float*)d_in[3];
    const float* sfilt = (const float*)d_in[4];
    float* out = (float*)d_out;

    // workspace layout (~26.7 MB)
    float* pb    = (float*)d_ws;                        // 16*XS_F f (12.6 MB)
    short* w_hi  = (short*)(pb + (size_t)16 * XS_F);    // WALL_F sh
    short* w_lo  = w_hi + (size_t)WALL_F;               // WALL_F sh
    short* xs_hi = w_lo + (size_t)WALL_F;               // XS_F sh
    short* xs_lo = xs_hi + (size_t)XS_F;                // XS_F sh
    float* c1    = (float*)(xs_lo + (size_t)XS_F);      // 589,824 f
    short* pT_hi = (short*)(c1 + (size_t)Bc * Kc * TD3);// XS_F sh
    short* pT_lo = pT_hi + (size_t)XS_F;                // XS_F sh

    const short* wo_hi = w_hi + (size_t)WQKV_F;
    const short* wo_lo = w_lo + (size_t)WQKV_F;

    hipLaunchKernelGGL(k1_fused,   dim3(2816), dim3(256), 0, stream,
                       x, sb, wqkv, wout, pb, w_hi, w_lo);
    hipLaunchKernelGGL(k1r_reduce, dim3(192),  dim3(256), 0, stream, pb, xs_hi, xs_lo);
    hipLaunchKernelGGL(k2_qkv,     dim3(288),  dim3(256), 0, stream, xs_hi, xs_lo, w_hi, w_lo, c1);
    hipLaunchKernelGGL(k4_proj,    dim3(192),  dim3(256), 0, stream, c1, sfilt, wo_hi, wo_lo, pT_hi, pT_lo);
    hipLaunchKernelGGL(k5_out,     dim3(2048), dim3(256), 0, stream, pT_hi, pT_lo, sb, out);
}